// Round 3
// baseline (1617.372 us; speedup 1.0000x reference)
//
#include <hip/hip_runtime.h>
#include <hip/hip_bf16.h>

typedef float f2 __attribute__((ext_vector_type(2)));
typedef float f4 __attribute__((ext_vector_type(4)));

#define BB 64
#define TT 2048
#define II 64
#define HH 128
#define OO 64

// One workgroup per (batch, direction). 256 threads:
//   recurrence role: j = tid>>1 (output unit 0..127), p = tid&1 (K-half)
//   out-proj role:   o = tid>>2 (output 0..63),       os = tid&3 (K-quarter)
// W_hh/W_ih/W_out slices live in registers; h and x_t broadcast via LDS
// double buffers; ONE __syncthreads per timestep. Out-projection runs one
// step behind the recurrence so it reads the stable h buffer (no extra
// barrier). Both directions atomicAdd into memset-zeroed d_out.
__global__ __launch_bounds__(256, 1)
void birnn_fused(const float* __restrict__ x,
                 const float* __restrict__ Wih_f, const float* __restrict__ Whh_f,
                 const float* __restrict__ bih_f, const float* __restrict__ bhh_f,
                 const float* __restrict__ Wih_b, const float* __restrict__ Whh_b,
                 const float* __restrict__ bih_b, const float* __restrict__ bhh_b,
                 const float* __restrict__ Wout, const float* __restrict__ bout,
                 float* __restrict__ out)
{
    const int tid = threadIdx.x;
    const int b   = blockIdx.x & (BB - 1);
    const int d   = blockIdx.x >> 6;

    const float* __restrict__ Wih = d ? Wih_b : Wih_f;
    const float* __restrict__ Whh = d ? Whh_b : Whh_f;
    const float* __restrict__ bih = d ? bih_b : bih_f;
    const float* __restrict__ bhh = d ? bhh_b : bhh_f;

    const int j  = tid >> 1;
    const int p  = tid & 1;
    const int o  = tid >> 2;
    const int os = tid & 3;

    __shared__ float hbuf[2][HH];
    __shared__ float xbuf[2][II];

    // ---- weights into registers (float2-packed: hope for v_pk_fma_f32) ----
    f2 whh[32], wih[16], wo[16];
    {
        const f4* s4 = (const f4*)(Whh + (size_t)j * HH + p * 64);
        #pragma unroll
        for (int m = 0; m < 16; ++m) {
            f4 v = s4[m];
            whh[2*m]   = (f2){v.x, v.y};
            whh[2*m+1] = (f2){v.z, v.w};
        }
    }
    {
        const f4* s4 = (const f4*)(Wih + (size_t)j * II + p * 32);
        #pragma unroll
        for (int m = 0; m < 8; ++m) {
            f4 v = s4[m];
            wih[2*m]   = (f2){v.x, v.y};
            wih[2*m+1] = (f2){v.z, v.w};
        }
    }
    {
        const f4* s4 = (const f4*)(Wout + (size_t)o * (2 * HH) + d * HH + os * 32);
        #pragma unroll
        for (int m = 0; m < 8; ++m) {
            f4 v = s4[m];
            wo[2*m]   = (f2){v.x, v.y};
            wo[2*m+1] = (f2){v.z, v.w};
        }
    }
    const float bj = bih[j] + bhh[j];
    const float bo = d ? 0.f : bout[o];   // forward dir owns b_out

    const float* __restrict__ xb   = x   + (size_t)b * TT * II;
    float*       __restrict__ outb = out + (size_t)b * TT * OO;
    const int t0 = d ? (TT - 1) : 0;
    const int dt = d ? -1 : 1;

    // ---- prologue: x_t0 into LDS, prefetch x_t1, h0 = 0 ----
    float xpre = 0.f;
    if (tid < II) {
        xbuf[0][tid] = xb[(size_t)t0 * II + tid];
        xpre = xb[(size_t)(t0 + dt) * II + tid];
    }
    if (tid < HH) hbuf[0][tid] = 0.f;
    __syncthreads();

    #pragma unroll 2
    for (int s = 0; s < TT; ++s) {
        const int cur = s & 1;
        const int nxt = cur ^ 1;

        // ---- out-projection for h_{s-1} (stable in hbuf[cur]) ----
        if (s > 0) {
            const f4* hv4 = (const f4*)(&hbuf[cur][os * 32]);
            f2 acc = (f2){0.f, 0.f};
            #pragma unroll
            for (int m = 0; m < 8; ++m) {
                f4 h4 = hv4[m];
                acc += wo[2*m]   * (f2){h4.x, h4.y};
                acc += wo[2*m+1] * (f2){h4.z, h4.w};
            }
            float v = acc.x + acc.y;
            v += __shfl_xor(v, 1);
            v += __shfl_xor(v, 2);
            if (os == 0) {
                const int tprev = t0 + dt * (s - 1);
                atomicAdd(&outb[(size_t)tprev * OO + o], v + bo);
            }
        }

        // ---- recurrence: z_j = Whh[j,:]h + Wih[j,:]x_t + b ----
        {
            const f4* hv4 = (const f4*)(&hbuf[cur][p * 64]);
            const f4* xv4 = (const f4*)(&xbuf[cur][p * 32]);
            f2 acc = (f2){0.f, 0.f};
            #pragma unroll
            for (int m = 0; m < 16; ++m) {
                f4 h4 = hv4[m];
                acc += whh[2*m]   * (f2){h4.x, h4.y};
                acc += whh[2*m+1] * (f2){h4.z, h4.w};
            }
            #pragma unroll
            for (int m = 0; m < 8; ++m) {
                f4 x4 = xv4[m];
                acc += wih[2*m]   * (f2){x4.x, x4.y};
                acc += wih[2*m+1] * (f2){x4.z, x4.w};
            }
            float z = acc.x + acc.y;
            z += __shfl_xor(z, 1);
            z += bj;
            // tanh(z) = 1 - 2/(e^{2z}+1); inf-safe for large |z|
            float e = __expf(2.f * z);
            float h = 1.f - __fdividef(2.f, e + 1.f);
            if (p == 0) hbuf[nxt][j] = h;
        }

        // ---- stage x_{s+1} into next buffer; prefetch x_{s+2} ----
        if (tid < II) {
            xbuf[nxt][tid] = xpre;
            if (s + 2 < TT) xpre = xb[(size_t)(t0 + dt * (s + 2)) * II + tid];
        }
        __syncthreads();
    }

    // ---- epilogue: out-projection for final h (in hbuf[TT&1]) ----
    {
        const f4* hv4 = (const f4*)(&hbuf[TT & 1][os * 32]);
        f2 acc = (f2){0.f, 0.f};
        #pragma unroll
        for (int m = 0; m < 8; ++m) {
            f4 h4 = hv4[m];
            acc += wo[2*m]   * (f2){h4.x, h4.y};
            acc += wo[2*m+1] * (f2){h4.z, h4.w};
        }
        float v = acc.x + acc.y;
        v += __shfl_xor(v, 1);
        v += __shfl_xor(v, 2);
        if (os == 0) {
            const int tlast = t0 + dt * (TT - 1);
            atomicAdd(&outb[(size_t)tlast * OO + o], v + bo);
        }
    }
}

extern "C" void kernel_launch(void* const* d_in, const int* in_sizes, int n_in,
                              void* d_out, int out_size, void* d_ws, size_t ws_size,
                              hipStream_t stream) {
    const float* x     = (const float*)d_in[0];
    const float* Wih_f = (const float*)d_in[1];
    const float* Whh_f = (const float*)d_in[2];
    const float* bih_f = (const float*)d_in[3];
    const float* bhh_f = (const float*)d_in[4];
    const float* Wih_b = (const float*)d_in[5];
    const float* Whh_b = (const float*)d_in[6];
    const float* bih_b = (const float*)d_in[7];
    const float* bhh_b = (const float*)d_in[8];
    const float* Wout  = (const float*)d_in[9];
    const float* bout  = (const float*)d_in[10];
    float* out = (float*)d_out;

    // Both directions atomicAdd into out — zero it first (capture-safe).
    hipMemsetAsync(d_out, 0, (size_t)out_size * sizeof(float), stream);

    birnn_fused<<<dim3(2 * BB), dim3(256), 0, stream>>>(
        x, Wih_f, Whh_f, bih_f, bhh_f,
        Wih_b, Whh_b, bih_b, bhh_b,
        Wout, bout, out);
}